// Round 4
// baseline (5889.456 us; speedup 1.0000x reference)
//
#include <hip/hip_runtime.h>
#include <hip/hip_bf16.h>
#include <math.h>

typedef __attribute__((ext_vector_type(8))) short short8;
typedef __attribute__((ext_vector_type(4))) float f32x4;

#define MFMA16(a,b,c) __builtin_amdgcn_mfma_f32_16x16x32_bf16((a),(b),(c),0,0,0)

__device__ __forceinline__ unsigned short f2bf(float f){
  unsigned int u = __builtin_bit_cast(unsigned int, f);
  u += 0x7fffu + ((u >> 16) & 1u);
  return (unsigned short)(u >> 16);
}

__device__ __forceinline__ void gload16(const void* g, void* lds){
  __builtin_amdgcn_global_load_lds(
      (const __attribute__((address_space(1))) unsigned int*)g,
      (__attribute__((address_space(3))) unsigned int*)lds, 16, 0, 0);
}

// ---------------- weight transpose + cast: in [K][N] f32 -> out [N][K] bf16 ----------------
__global__ __launch_bounds__(256) void k_transpose_cast(const float* __restrict__ in,
    unsigned short* __restrict__ out, int K, int N)
{
  __shared__ unsigned short tile[32][33];
  const int tx = threadIdx.x, ty = threadIdx.y;
  const int n0 = blockIdx.x * 32, k0 = blockIdx.y * 32;
  #pragma unroll
  for (int i = 0; i < 4; i++) {
    int k = k0 + ty + i*8;
    tile[ty + i*8][tx] = f2bf(in[(size_t)k * N + n0 + tx]);
  }
  __syncthreads();
  #pragma unroll
  for (int i = 0; i < 4; i++) {
    int n = n0 + ty + i*8;
    out[(size_t)n * K + k0 + tx] = tile[tx][ty + i*8];
  }
}

// ---------------- layernorm: x [rows][1024] f32 -> out bf16 ----------------
__global__ __launch_bounds__(256) void k_layernorm(const float* __restrict__ x,
    const float* __restrict__ g, const float* __restrict__ b,
    unsigned short* __restrict__ out)
{
  const int row = blockIdx.x;
  const int t = threadIdx.x;
  const float4 v = ((const float4*)(x + (size_t)row * 1024))[t];
  float s  = v.x + v.y + v.z + v.w;
  float s2 = v.x*v.x + v.y*v.y + v.z*v.z + v.w*v.w;
  #pragma unroll
  for (int m = 1; m < 64; m <<= 1) {
    s  += __shfl_xor(s,  m);
    s2 += __shfl_xor(s2, m);
  }
  __shared__ float red[2][4];
  const int wid = t >> 6, lane = t & 63;
  if (lane == 0) { red[0][wid] = s; red[1][wid] = s2; }
  __syncthreads();
  s  = red[0][0] + red[0][1] + red[0][2] + red[0][3];
  s2 = red[1][0] + red[1][1] + red[1][2] + red[1][3];
  const float mu = s * (1.0f / 1024.0f);
  const float var = s2 * (1.0f / 1024.0f) - mu * mu;
  const float rstd = rsqrtf(var + 1e-6f);
  const float4 gv = ((const float4*)g)[t];
  const float4 bv = ((const float4*)b)[t];
  ushort4 o;
  o.x = f2bf((v.x - mu) * rstd * gv.x + bv.x);
  o.y = f2bf((v.y - mu) * rstd * gv.y + bv.y);
  o.z = f2bf((v.z - mu) * rstd * gv.z + bv.z);
  o.w = f2bf((v.w - mu) * rstd * gv.w + bv.w);
  ((ushort4*)(out + (size_t)row * 1024))[t] = o;
}

// ---------------- 256x256 MFMA GEMM, counted-vmcnt dbuf + XCD swizzle + LDS-bounce epilogue ----
// EPI 0: QKV mode: bn<8 -> qk buffer (stride 2048) bf16; bn>=8 -> vT[b][h][d][n] bf16
// EPI 1: out bf16 = gelu_exact(acc + bias)
// EPI 2: out f32  = resid + (acc + bias) * lsg
template<int EPI>
__global__ __launch_bounds__(512, 2) void k_gemm256(
    const unsigned short* __restrict__ A,
    const unsigned short* __restrict__ Bt,
    const float* __restrict__ bias,
    const float* __restrict__ resid,
    const float* __restrict__ lsg,
    void* __restrict__ outp,
    unsigned short* __restrict__ vtp,
    int M, int N, int K, int nbn)
{
  __shared__ __align__(16) char smem[131072];
  // K-loop overlay: A buffers at [0,64K), B buffers at [64K,128K)
  unsigned short* AsmB[2] = { (unsigned short*)smem,
                              (unsigned short*)(smem + 32768) };
  unsigned short* BsmB[2] = { (unsigned short*)(smem + 65536),
                              (unsigned short*)(smem + 98304) };
  // epilogue overlay: f32 [256][68]
  float* Clds = (float*)smem;

  // XCD-chunked bijective swizzle: XCD x owns bm rows [x*mrows, (x+1)*mrows),
  // bn-major issue order within XCD (concurrent blocks share A-rows AND B-cols).
  const int bid = blockIdx.x;
  const int mrows = (gridDim.x >> 3) / nbn;
  const int xcd = bid & 7, l = bid >> 3;
  const int bm = xcd * mrows + (l % mrows);
  const int bn = l / mrows;

  const int t = threadIdx.x, lane = t & 63;
  const int wid = t >> 6, wm = wid >> 2, wn = wid & 3;
  const int fr = lane & 15, fg = lane >> 4;

  // staging map: 2048 16B chunks per 256x64 tile, 4 per thread.
  // LDS dest linear; global source chunk pre-swizzled (c ^ row&7) so the
  // frag reads apply the same XOR -> conflict-free ds_read_b128 (rule #21).
  size_t aOff[4], bOff[4];
  int slotArr[4];
  #pragma unroll
  for (int i = 0; i < 4; i++) {
    const int slot = i * 512 + t;
    const int row = slot >> 3, c = slot & 7;
    const int cs = c ^ (row & 7);
    slotArr[i] = slot;
    aOff[i] = (size_t)((size_t)bm * 256 + row) * K + cs * 8;
    bOff[i] = (size_t)((size_t)bn * 256 + row) * K + cs * 8;
  }

  f32x4 acc[8][4] = {};
  const int NT = K >> 6;   // K-tiles of 64; even (16 or 64)

  #pragma unroll
  for (int i = 0; i < 4; i++) {
    gload16(A  + aOff[i], (char*)AsmB[0] + slotArr[i] * 16);
    gload16(Bt + bOff[i], (char*)BsmB[0] + slotArr[i] * 16);
  }
  #pragma unroll
  for (int i = 0; i < 4; i++) {
    gload16(A  + aOff[i] + 64, (char*)AsmB[1] + slotArr[i] * 16);
    gload16(Bt + bOff[i] + 64, (char*)BsmB[1] + slotArr[i] * 16);
  }

  auto tile_step = [&](int tt, int buf) {
    if (tt == NT - 1) asm volatile("s_waitcnt vmcnt(0)" ::: "memory");
    else              asm volatile("s_waitcnt vmcnt(8)" ::: "memory");
    asm volatile("s_barrier" ::: "memory");
    #pragma unroll
    for (int kk = 0; kk < 2; kk++) {
      short8 af[8], bfv[4];
      #pragma unroll
      for (int m = 0; m < 8; m++) {
        const int row = wm * 128 + m * 16 + fr;
        af[m] = *(const short8*)&AsmB[buf][row * 64 + (((kk*4 + fg) ^ (fr & 7)) * 8)];
      }
      #pragma unroll
      for (int n = 0; n < 4; n++) {
        const int row = wn * 64 + n * 16 + fr;
        bfv[n] = *(const short8*)&BsmB[buf][row * 64 + (((kk*4 + fg) ^ (fr & 7)) * 8)];
      }
      __builtin_amdgcn_s_setprio(1);
      #pragma unroll
      for (int m = 0; m < 8; m++)
        #pragma unroll
        for (int n = 0; n < 4; n++)
          acc[m][n] = MFMA16(af[m], bfv[n], acc[m][n]);
      __builtin_amdgcn_s_setprio(0);
    }
    asm volatile("s_barrier" ::: "memory");
    if (tt + 2 < NT) {
      const size_t kofs = (size_t)(tt + 2) * 64;
      #pragma unroll
      for (int i = 0; i < 4; i++) {
        gload16(A  + aOff[i] + kofs, (char*)AsmB[buf] + slotArr[i] * 16);
        gload16(Bt + bOff[i] + kofs, (char*)BsmB[buf] + slotArr[i] * 16);
      }
    }
  };

  for (int tt = 0; tt < NT; tt += 2) {
    tile_step(tt, 0);
    tile_step(tt + 1, 1);
  }

  // ---- LDS-bounce epilogue: per n, stage 256x64 f32 tile, emit coalesced stores ----
  const int lrow0 = wm * 128 + fg * 4;   // LDS row base for this lane's frags
  const int lcol  = wn * 16 + fr;        // LDS col for this lane
  #pragma unroll 1
  for (int n = 0; n < 4; n++) {
    const int gc = bn * 256 + wn * 64 + n * 16 + fr;   // this lane's global col
    const float bcol = bias[gc];
    float lscale = 0.f;
    if (EPI == 2) lscale = lsg[gc];
    #pragma unroll
    for (int m = 0; m < 8; m++) {
      #pragma unroll
      for (int r = 0; r < 4; r++) {
        float v = acc[m][n][r] + bcol;
        if (EPI == 1) v = 0.5f * v * (1.0f + erff(v * 0.70710678118654752f));
        if (EPI == 2) v = v * lscale;
        Clds[(lrow0 + m * 16 + r) * 68 + lcol] = v;
      }
    }
    __syncthreads();

    if (EPI == 2) {
      // f32 out with residual: 8 iters x float4
      #pragma unroll
      for (int it = 0; it < 8; it++) {
        const int row = it * 32 + (t >> 4);
        const int seg = (t & 15) * 4;
        const float4 c = *(const float4*)&Clds[row * 68 + seg];
        const int grow = bm * 256 + row;
        const int gcol = bn * 256 + (seg >> 4) * 64 + n * 16 + (seg & 15);
        const float4 rv = *(const float4*)((const float*)resid + (size_t)grow * N + gcol);
        float4 o;
        o.x = rv.x + c.x; o.y = rv.y + c.y; o.z = rv.z + c.z; o.w = rv.w + c.w;
        *(float4*)((float*)outp + (size_t)grow * N + gcol) = o;
      }
    } else if (EPI == 1 || (EPI == 0 && bn < 8)) {
      // bf16 out, row-major: 4 iters x 8 elems (16B store)
      const size_t stride = (EPI == 0) ? 2048 : (size_t)N;
      #pragma unroll
      for (int it = 0; it < 4; it++) {
        const int row = it * 64 + (t >> 3);
        const int seg = (t & 7) * 8;
        const float4 c0 = *(const float4*)&Clds[row * 68 + seg];
        const float4 c1 = *(const float4*)&Clds[row * 68 + seg + 4];
        short8 o;
        o[0] = (short)f2bf(c0.x); o[1] = (short)f2bf(c0.y);
        o[2] = (short)f2bf(c0.z); o[3] = (short)f2bf(c0.w);
        o[4] = (short)f2bf(c1.x); o[5] = (short)f2bf(c1.y);
        o[6] = (short)f2bf(c1.z); o[7] = (short)f2bf(c1.w);
        const int grow = bm * 256 + row;
        const int gcol = bn * 256 + (seg >> 4) * 64 + n * 16 + (seg & 15);
        *(short8*)((unsigned short*)outp + (size_t)grow * stride + gcol) = o;
      }
    } else {
      // EPI 0, bn >= 8: V^T output — transpose-read LDS, store 8 tokens/lane
      const int c = t & 63;            // LDS col (within this n's 64)
      const int rg = t >> 6;           // wave id -> row sub-block
      const int gcol = bn * 256 + (c >> 4) * 64 + n * 16 + (c & 15);
      const int d = gcol - 2048, hh = d >> 6, dd = d & 63;
      const int bb = bm >> 2, nnb = (bm & 3) * 256;
      #pragma unroll
      for (int ii = 0; ii < 4; ii++) {
        const int row0 = ii * 64 + rg * 8;
        short8 o;
        #pragma unroll
        for (int j = 0; j < 8; j++)
          o[j] = (short)f2bf(Clds[(row0 + j) * 68 + c]);
        *(short8*)(vtp + (((size_t)bb * 16 + hh) * 64 + dd) * 1024 + nnb + row0) = o;
      }
    }
    __syncthreads();
  }
}

// ---------------- flash attention (no 1/sqrt(d) scale, faithful to ref) ----------------
// qk: [16384][2048] bf16 ; vT: [b][h][64 d][1024 n] bf16 ; out: [16384][1024] bf16
__global__ __launch_bounds__(512) void k_attn(const unsigned short* __restrict__ qk,
                                              const unsigned short* __restrict__ vT,
                                              unsigned short* __restrict__ out)
{
  const int qt = blockIdx.x;       // 0..3  (q tile of 256 rows)
  const int bh = blockIdx.y;       // 0..255
  const int b = bh >> 4, h = bh & 15;
  const int t = threadIdx.x, lane = t & 63, wid = t >> 6;
  const int fr = lane & 15, fg = lane >> 4;
  const int q0 = qt * 256 + wid * 32;

  __shared__ __align__(16) unsigned short Ksm[64 * 64];
  __shared__ __align__(16) unsigned short Vsm[64 * 64];
  __shared__ __align__(16) unsigned short plds[8][32][72];

  const size_t qbase = (size_t)b * 1024 * 2048 + (size_t)h * 64;
  const size_t kbase = qbase + 1024;
  const size_t vbase = (size_t)bh * 64 * 1024;

  short8 qf[2][2];
  #pragma unroll
  for (int m = 0; m < 2; m++)
    #pragma unroll
    for (int kh = 0; kh < 2; kh++)
      qf[m][kh] = *(const short8*)(qk + qbase + (size_t)(q0 + m*16 + fr) * 2048
                                   + kh*32 + fg*8);

  f32x4 oacc[2][4] = {};
  float mrow[2][4], lrow[2][4];
  #pragma unroll
  for (int m = 0; m < 2; m++)
    #pragma unroll
    for (int r = 0; r < 4; r++) { mrow[m][r] = -1e30f; lrow[m][r] = 0.f; }

  const int srow = t >> 3, sc = t & 7;
  const int scs = sc ^ (srow & 7);

  for (int kv0 = 0; kv0 < 1024; kv0 += 64) {
    __syncthreads();
    gload16(qk + kbase + (size_t)(kv0 + srow) * 2048 + scs*8, (char*)Ksm + t*16);
    gload16(vT + vbase + (size_t)srow * 1024 + kv0 + scs*8,   (char*)Vsm + t*16);
    __syncthreads();

    f32x4 sacc[2][4] = {};
    #pragma unroll
    for (int n = 0; n < 4; n++) {
      #pragma unroll
      for (int kh = 0; kh < 2; kh++) {
        const int krow = n*16 + fr;
        short8 kf = *(const short8*)&Ksm[krow*64 + (((kh*4 + fg) ^ (krow & 7)) * 8)];
        sacc[0][n] = MFMA16(qf[0][kh], kf, sacc[0][n]);
        sacc[1][n] = MFMA16(qf[1][kh], kf, sacc[1][n]);
      }
    }

    #pragma unroll
    for (int m = 0; m < 2; m++) {
      float pm[4];
      #pragma unroll
      for (int r = 0; r < 4; r++)
        pm[r] = fmaxf(fmaxf(sacc[m][0][r], sacc[m][1][r]),
                      fmaxf(sacc[m][2][r], sacc[m][3][r]));
      #pragma unroll
      for (int msk = 1; msk < 16; msk <<= 1)
        #pragma unroll
        for (int r = 0; r < 4; r++) pm[r] = fmaxf(pm[r], __shfl_xor(pm[r], msk));
      float corr[4];
      #pragma unroll
      for (int r = 0; r < 4; r++) {
        float mn = fmaxf(mrow[m][r], pm[r]);
        corr[r] = __expf(mrow[m][r] - mn);
        mrow[m][r] = mn;
      }
      float psum[4] = {0.f, 0.f, 0.f, 0.f};
      #pragma unroll
      for (int n = 0; n < 4; n++)
        #pragma unroll
        for (int r = 0; r < 4; r++) {
          float p = __expf(sacc[m][n][r] - mrow[m][r]);
          sacc[m][n][r] = p;
          psum[r] += p;
        }
      #pragma unroll
      for (int msk = 1; msk < 16; msk <<= 1)
        #pragma unroll
        for (int r = 0; r < 4; r++) psum[r] += __shfl_xor(psum[r], msk);
      #pragma unroll
      for (int r = 0; r < 4; r++) lrow[m][r] = lrow[m][r] * corr[r] + psum[r];
      #pragma unroll
      for (int d16 = 0; d16 < 4; d16++)
        #pragma unroll
        for (int r = 0; r < 4; r++) oacc[m][d16][r] *= corr[r];
      #pragma unroll
      for (int n = 0; n < 4; n++)
        #pragma unroll
        for (int r = 0; r < 4; r++)
          plds[wid][m*16 + fg*4 + r][n*16 + fr] = f2bf(sacc[m][n][r]);
    }

    short8 pf[2][2];
    #pragma unroll
    for (int m = 0; m < 2; m++)
      #pragma unroll
      for (int kh = 0; kh < 2; kh++)
        pf[m][kh] = *(const short8*)&plds[wid][m*16 + fr][kh*32 + fg*8];

    #pragma unroll
    for (int d16 = 0; d16 < 4; d16++) {
      #pragma unroll
      for (int kh = 0; kh < 2; kh++) {
        const int vrow = d16*16 + fr;
        short8 vf = *(const short8*)&Vsm[vrow*64 + (((kh*4 + fg) ^ (vrow & 7)) * 8)];
        oacc[0][d16] = MFMA16(pf[0][kh], vf, oacc[0][d16]);
        oacc[1][d16] = MFMA16(pf[1][kh], vf, oacc[1][d16]);
      }
    }
  }

  #pragma unroll
  for (int m = 0; m < 2; m++) {
    float inv[4];
    #pragma unroll
    for (int r = 0; r < 4; r++) inv[r] = 1.0f / lrow[m][r];
    #pragma unroll
    for (int d16 = 0; d16 < 4; d16++) {
      #pragma unroll
      for (int r = 0; r < 4; r++) {
        const int qrow = q0 + m*16 + fg*4 + r;
        const int col = h*64 + d16*16 + fr;
        out[(size_t)(b * 1024 + qrow) * 1024 + col] = f2bf(oacc[m][d16][r] * inv[r]);
      }
    }
  }
}

// ---------------- host launch ----------------
extern "C" void kernel_launch(void* const* d_in, const int* in_sizes, int n_in,
                              void* d_out, int out_size, void* d_ws, size_t ws_size,
                              hipStream_t stream) {
  const float* x      = (const float*)d_in[0];
  const float* ln1_g  = (const float*)d_in[1];
  const float* ln1_b  = (const float*)d_in[2];
  const float* qkv_w  = (const float*)d_in[3];
  const float* qkv_b  = (const float*)d_in[4];
  const float* proj_w = (const float*)d_in[5];
  const float* proj_b = (const float*)d_in[6];
  const float* ls1_g  = (const float*)d_in[7];
  const float* ln2_g  = (const float*)d_in[8];
  const float* ln2_b  = (const float*)d_in[9];
  const float* fc1_w  = (const float*)d_in[10];
  const float* fc1_b  = (const float*)d_in[11];
  const float* fc2_w  = (const float*)d_in[12];
  const float* fc2_b  = (const float*)d_in[13];
  const float* ls2_g  = (const float*)d_in[14];

  char* w = (char*)d_ws;
  unsigned short* wqkvT  = (unsigned short*)(w + 0);                    //  6,291,456
  unsigned short* wprojT = (unsigned short*)(w + 6291456);              //  2,097,152
  unsigned short* wfc1T  = (unsigned short*)(w + 8388608);              //  8,388,608
  unsigned short* wfc2T  = (unsigned short*)(w + 16777216);             //  8,388,608
  float*          x1     = (float*)(w + 25165824);                      // 67,108,864
  unsigned short* h1     = (unsigned short*)(w + 92274688);             // 33,554,432 (reused as h2)
  unsigned short* qkbuf  = (unsigned short*)(w + 125829120);            // 67,108,864 [16384][2048]
  unsigned short* vtbuf  = (unsigned short*)(w + 192937984);            // 33,554,432 [256][64][1024]
  unsigned short* attno  = (unsigned short*)(w + 226492416);            // 33,554,432
  unsigned short* h3     = (unsigned short*)(w + 125829120);            // 134,217,728 (overlays qk+vT)

  dim3 tb32(32, 8);
  k_transpose_cast<<<dim3(3072/32, 1024/32), tb32, 0, stream>>>(qkv_w,  wqkvT, 1024, 3072);
  k_transpose_cast<<<dim3(1024/32, 1024/32), tb32, 0, stream>>>(proj_w, wprojT, 1024, 1024);
  k_transpose_cast<<<dim3(4096/32, 1024/32), tb32, 0, stream>>>(fc1_w,  wfc1T, 1024, 4096);
  k_transpose_cast<<<dim3(1024/32, 4096/32), tb32, 0, stream>>>(fc2_w,  wfc2T, 4096, 1024);

  // LN1
  k_layernorm<<<16384, 256, 0, stream>>>(x, ln1_g, ln1_b, h1);
  // QKV = h1 @ qkv_w + qkv_b ; Q,K -> qkbuf, V -> vtbuf transposed
  k_gemm256<0><<<64*12, 512, 0, stream>>>(h1, wqkvT, qkv_b, nullptr, nullptr,
                                          qkbuf, vtbuf, 16384, 3072, 1024, 12);
  // attention
  k_attn<<<dim3(4, 256), 512, 0, stream>>>(qkbuf, vtbuf, attno);
  // x1 = x + (attn @ proj_w + proj_b) * ls1_g
  k_gemm256<2><<<64*4, 512, 0, stream>>>(attno, wprojT, proj_b, x, ls1_g,
                                         x1, nullptr, 16384, 1024, 1024, 4);
  // LN2
  k_layernorm<<<16384, 256, 0, stream>>>(x1, ln2_g, ln2_b, h1);
  // h3 = gelu(h2 @ fc1_w + fc1_b)
  k_gemm256<1><<<64*16, 512, 0, stream>>>(h1, wfc1T, fc1_b, nullptr, nullptr,
                                          h3, nullptr, 16384, 4096, 1024, 16);
  // out = x1 + (h3 @ fc2_w + fc2_b) * ls2_g
  k_gemm256<2><<<64*4, 512, 0, stream>>>(h3, wfc2T, fc2_b, x1, ls2_g,
                                         (float*)d_out, nullptr, 16384, 1024, 4096, 4);
}

// Round 5
// 1108.755 us; speedup vs baseline: 5.3118x; 5.3118x over previous
//
#include <hip/hip_runtime.h>
#include <hip/hip_bf16.h>
#include <math.h>

typedef __attribute__((ext_vector_type(8))) short short8;
typedef __attribute__((ext_vector_type(4))) float f32x4;

#define MFMA16(a,b,c) __builtin_amdgcn_mfma_f32_16x16x32_bf16((a),(b),(c),0,0,0)

__device__ __forceinline__ unsigned short f2bf(float f){
  unsigned int u = __builtin_bit_cast(unsigned int, f);
  u += 0x7fffu + ((u >> 16) & 1u);
  return (unsigned short)(u >> 16);
}

__device__ __forceinline__ void gload16(const void* g, void* lds){
  __builtin_amdgcn_global_load_lds(
      (const __attribute__((address_space(1))) unsigned int*)g,
      (__attribute__((address_space(3))) unsigned int*)lds, 16, 0, 0);
}

// ---------------- weight transpose + cast: in [K][N] f32 -> out [N][K] bf16 ----------------
__global__ __launch_bounds__(256) void k_transpose_cast(const float* __restrict__ in,
    unsigned short* __restrict__ out, int K, int N)
{
  __shared__ unsigned short tile[32][33];
  const int tx = threadIdx.x, ty = threadIdx.y;
  const int n0 = blockIdx.x * 32, k0 = blockIdx.y * 32;
  #pragma unroll
  for (int i = 0; i < 4; i++) {
    int k = k0 + ty + i*8;
    tile[ty + i*8][tx] = f2bf(in[(size_t)k * N + n0 + tx]);
  }
  __syncthreads();
  #pragma unroll
  for (int i = 0; i < 4; i++) {
    int n = n0 + ty + i*8;
    out[(size_t)n * K + k0 + tx] = tile[tx][ty + i*8];
  }
}

// ---------------- layernorm: x [rows][1024] f32 -> out bf16 ----------------
__global__ __launch_bounds__(256) void k_layernorm(const float* __restrict__ x,
    const float* __restrict__ g, const float* __restrict__ b,
    unsigned short* __restrict__ out)
{
  const int row = blockIdx.x;
  const int t = threadIdx.x;
  const float4 v = ((const float4*)(x + (size_t)row * 1024))[t];
  float s  = v.x + v.y + v.z + v.w;
  float s2 = v.x*v.x + v.y*v.y + v.z*v.z + v.w*v.w;
  #pragma unroll
  for (int m = 1; m < 64; m <<= 1) {
    s  += __shfl_xor(s,  m);
    s2 += __shfl_xor(s2, m);
  }
  __shared__ float red[2][4];
  const int wid = t >> 6, lane = t & 63;
  if (lane == 0) { red[0][wid] = s; red[1][wid] = s2; }
  __syncthreads();
  s  = red[0][0] + red[0][1] + red[0][2] + red[0][3];
  s2 = red[1][0] + red[1][1] + red[1][2] + red[1][3];
  const float mu = s * (1.0f / 1024.0f);
  const float var = s2 * (1.0f / 1024.0f) - mu * mu;
  const float rstd = rsqrtf(var + 1e-6f);
  const float4 gv = ((const float4*)g)[t];
  const float4 bv = ((const float4*)b)[t];
  ushort4 o;
  o.x = f2bf((v.x - mu) * rstd * gv.x + bv.x);
  o.y = f2bf((v.y - mu) * rstd * gv.y + bv.y);
  o.z = f2bf((v.z - mu) * rstd * gv.z + bv.z);
  o.w = f2bf((v.w - mu) * rstd * gv.w + bv.w);
  ((ushort4*)(out + (size_t)row * 1024))[t] = o;
}

// ---------------- 256x256 MFMA GEMM, counted-vmcnt dbuf + XCD swizzle + LDS-bounce epilogue ----
// EPI 0: QKV mode: bn<8 -> qk buffer (stride 2048) bf16; bn>=8 -> vT[b][h][d][n] bf16
// EPI 1: out bf16 = gelu_exact(acc + bias)
// EPI 2: out f32  = resid + (acc + bias) * lsg
template<int EPI>
__global__ __launch_bounds__(512, 2) void k_gemm256(
    const unsigned short* __restrict__ A,
    const unsigned short* __restrict__ Bt,
    const float* __restrict__ bias,
    const float* __restrict__ resid,
    const float* __restrict__ lsg,
    void* __restrict__ outp,
    unsigned short* __restrict__ vtp,
    int M, int N, int K, int nbn)
{
  __shared__ __align__(16) char smem[131072];
  // K-loop overlay: A buffers at [0,64K), B buffers at [64K,128K)
  unsigned short* AsmB[2] = { (unsigned short*)smem,
                              (unsigned short*)(smem + 32768) };
  unsigned short* BsmB[2] = { (unsigned short*)(smem + 65536),
                              (unsigned short*)(smem + 98304) };
  // epilogue overlay: f32 [256][68]
  float* Clds = (float*)smem;

  // XCD-chunked bijective swizzle: XCD x owns bm rows [x*mrows, (x+1)*mrows),
  // bn-major issue order within XCD (concurrent blocks share A-rows AND B-cols).
  const int bid = blockIdx.x;
  const int mrows = (gridDim.x >> 3) / nbn;
  const int xcd = bid & 7, l = bid >> 3;
  const int bm = xcd * mrows + (l % mrows);
  const int bn = l / mrows;

  const int t = threadIdx.x, lane = t & 63;
  const int wid = t >> 6, wm = wid >> 2, wn = wid & 3;
  const int fr = lane & 15, fg = lane >> 4;

  // staging map: 2048 16B chunks per 256x64 tile, 4 per thread.
  // LDS dest linear; global source chunk pre-swizzled (c ^ row&7) so the
  // frag reads apply the same XOR -> conflict-free ds_read_b128 (rule #21).
  size_t aOff[4], bOff[4];
  int slotArr[4];
  #pragma unroll
  for (int i = 0; i < 4; i++) {
    const int slot = i * 512 + t;
    const int row = slot >> 3, c = slot & 7;
    const int cs = c ^ (row & 7);
    slotArr[i] = slot;
    aOff[i] = (size_t)((size_t)bm * 256 + row) * K + cs * 8;
    bOff[i] = (size_t)((size_t)bn * 256 + row) * K + cs * 8;
  }

  f32x4 acc[8][4] = {};
  const int NT = K >> 6;   // K-tiles of 64; even (16 or 64)

  #pragma unroll
  for (int i = 0; i < 4; i++) {
    gload16(A  + aOff[i], (char*)AsmB[0] + slotArr[i] * 16);
    gload16(Bt + bOff[i], (char*)BsmB[0] + slotArr[i] * 16);
  }
  #pragma unroll
  for (int i = 0; i < 4; i++) {
    gload16(A  + aOff[i] + 64, (char*)AsmB[1] + slotArr[i] * 16);
    gload16(Bt + bOff[i] + 64, (char*)BsmB[1] + slotArr[i] * 16);
  }

  auto tile_step = [&](int tt, int buf) {
    if (tt == NT - 1) asm volatile("s_waitcnt vmcnt(0)" ::: "memory");
    else              asm volatile("s_waitcnt vmcnt(8)" ::: "memory");
    asm volatile("s_barrier" ::: "memory");
    #pragma unroll
    for (int kk = 0; kk < 2; kk++) {
      short8 af[8], bfv[4];
      #pragma unroll
      for (int m = 0; m < 8; m++) {
        const int row = wm * 128 + m * 16 + fr;
        af[m] = *(const short8*)&AsmB[buf][row * 64 + (((kk*4 + fg) ^ (fr & 7)) * 8)];
      }
      #pragma unroll
      for (int n = 0; n < 4; n++) {
        const int row = wn * 64 + n * 16 + fr;
        bfv[n] = *(const short8*)&BsmB[buf][row * 64 + (((kk*4 + fg) ^ (fr & 7)) * 8)];
      }
      __builtin_amdgcn_s_setprio(1);
      #pragma unroll
      for (int m = 0; m < 8; m++)
        #pragma unroll
        for (int n = 0; n < 4; n++)
          acc[m][n] = MFMA16(af[m], bfv[n], acc[m][n]);
      __builtin_amdgcn_s_setprio(0);
    }
    asm volatile("s_barrier" ::: "memory");
    if (tt + 2 < NT) {
      const size_t kofs = (size_t)(tt + 2) * 64;
      #pragma unroll
      for (int i = 0; i < 4; i++) {
        gload16(A  + aOff[i] + kofs, (char*)AsmB[buf] + slotArr[i] * 16);
        gload16(Bt + bOff[i] + kofs, (char*)BsmB[buf] + slotArr[i] * 16);
      }
    }
  };

  for (int tt = 0; tt < NT; tt += 2) {
    tile_step(tt, 0);
    tile_step(tt + 1, 1);
  }

  // ---- LDS-bounce epilogue: per n (STATIC — full unroll, rule #20), stage
  // 256x64 f32 tile in LDS, emit coalesced stores ----
  const int lrow0 = wm * 128 + fg * 4;   // LDS row base for this lane's frags
  const int lcol  = wn * 16 + fr;        // LDS col for this lane
  #pragma unroll
  for (int n = 0; n < 4; n++) {
    const int gc = bn * 256 + wn * 64 + n * 16 + fr;   // this lane's global col
    const float bcol = bias[gc];
    float lscale = 0.f;
    if (EPI == 2) lscale = lsg[gc];
    #pragma unroll
    for (int m = 0; m < 8; m++) {
      #pragma unroll
      for (int r = 0; r < 4; r++) {
        float v = acc[m][n][r] + bcol;
        if (EPI == 1) v = 0.5f * v * (1.0f + erff(v * 0.70710678118654752f));
        if (EPI == 2) v = v * lscale;
        Clds[(lrow0 + m * 16 + r) * 68 + lcol] = v;
      }
    }
    __syncthreads();

    if (EPI == 2) {
      // f32 out with residual: 8 iters x float4
      #pragma unroll
      for (int it = 0; it < 8; it++) {
        const int row = it * 32 + (t >> 4);
        const int seg = (t & 15) * 4;
        const float4 c = *(const float4*)&Clds[row * 68 + seg];
        const int grow = bm * 256 + row;
        const int gcol = bn * 256 + (seg >> 4) * 64 + n * 16 + (seg & 15);
        const float4 rv = *(const float4*)((const float*)resid + (size_t)grow * N + gcol);
        float4 o;
        o.x = rv.x + c.x; o.y = rv.y + c.y; o.z = rv.z + c.z; o.w = rv.w + c.w;
        *(float4*)((float*)outp + (size_t)grow * N + gcol) = o;
      }
    } else if (EPI == 1 || (EPI == 0 && bn < 8)) {
      // bf16 out, row-major: 4 iters x 8 elems (16B store)
      const size_t stride = (EPI == 0) ? 2048 : (size_t)N;
      #pragma unroll
      for (int it = 0; it < 4; it++) {
        const int row = it * 64 + (t >> 3);
        const int seg = (t & 7) * 8;
        const float4 c0 = *(const float4*)&Clds[row * 68 + seg];
        const float4 c1 = *(const float4*)&Clds[row * 68 + seg + 4];
        short8 o;
        o[0] = (short)f2bf(c0.x); o[1] = (short)f2bf(c0.y);
        o[2] = (short)f2bf(c0.z); o[3] = (short)f2bf(c0.w);
        o[4] = (short)f2bf(c1.x); o[5] = (short)f2bf(c1.y);
        o[6] = (short)f2bf(c1.z); o[7] = (short)f2bf(c1.w);
        const int grow = bm * 256 + row;
        const int gcol = bn * 256 + (seg >> 4) * 64 + n * 16 + (seg & 15);
        *(short8*)((unsigned short*)outp + (size_t)grow * stride + gcol) = o;
      }
    } else {
      // EPI 0, bn >= 8: V^T output — transpose-read LDS, store 8 tokens/lane
      const int c = t & 63;            // LDS col (within this n's 64)
      const int rg = t >> 6;           // wave id -> row sub-block
      const int gcol = bn * 256 + (c >> 4) * 64 + n * 16 + (c & 15);
      const int d = gcol - 2048, hh = d >> 6, dd = d & 63;
      const int bb = bm >> 2, nnb = (bm & 3) * 256;
      #pragma unroll
      for (int ii = 0; ii < 4; ii++) {
        const int row0 = ii * 64 + rg * 8;
        short8 o;
        #pragma unroll
        for (int j = 0; j < 8; j++)
          o[j] = (short)f2bf(Clds[(row0 + j) * 68 + c]);
        *(short8*)(vtp + (((size_t)bb * 16 + hh) * 64 + dd) * 1024 + nnb + row0) = o;
      }
    }
    __syncthreads();
  }
}

// ---------------- flash attention (no 1/sqrt(d) scale, faithful to ref) ----------------
// qk: [16384][2048] bf16 ; vT: [b][h][64 d][1024 n] bf16 ; out: [16384][1024] bf16
__global__ __launch_bounds__(512) void k_attn(const unsigned short* __restrict__ qk,
                                              const unsigned short* __restrict__ vT,
                                              unsigned short* __restrict__ out)
{
  const int qt = blockIdx.x;       // 0..3  (q tile of 256 rows)
  const int bh = blockIdx.y;       // 0..255
  const int b = bh >> 4, h = bh & 15;
  const int t = threadIdx.x, lane = t & 63, wid = t >> 6;
  const int fr = lane & 15, fg = lane >> 4;
  const int q0 = qt * 256 + wid * 32;

  __shared__ __align__(16) unsigned short Ksm[64 * 64];
  __shared__ __align__(16) unsigned short Vsm[64 * 64];
  __shared__ __align__(16) unsigned short plds[8][32][72];

  const size_t qbase = (size_t)b * 1024 * 2048 + (size_t)h * 64;
  const size_t kbase = qbase + 1024;
  const size_t vbase = (size_t)bh * 64 * 1024;

  short8 qf[2][2];
  #pragma unroll
  for (int m = 0; m < 2; m++)
    #pragma unroll
    for (int kh = 0; kh < 2; kh++)
      qf[m][kh] = *(const short8*)(qk + qbase + (size_t)(q0 + m*16 + fr) * 2048
                                   + kh*32 + fg*8);

  f32x4 oacc[2][4] = {};
  float mrow[2][4], lrow[2][4];
  #pragma unroll
  for (int m = 0; m < 2; m++)
    #pragma unroll
    for (int r = 0; r < 4; r++) { mrow[m][r] = -1e30f; lrow[m][r] = 0.f; }

  const int srow = t >> 3, sc = t & 7;
  const int scs = sc ^ (srow & 7);

  for (int kv0 = 0; kv0 < 1024; kv0 += 64) {
    __syncthreads();
    gload16(qk + kbase + (size_t)(kv0 + srow) * 2048 + scs*8, (char*)Ksm + t*16);
    gload16(vT + vbase + (size_t)srow * 1024 + kv0 + scs*8,   (char*)Vsm + t*16);
    __syncthreads();

    f32x4 sacc[2][4] = {};
    #pragma unroll
    for (int n = 0; n < 4; n++) {
      #pragma unroll
      for (int kh = 0; kh < 2; kh++) {
        const int krow = n*16 + fr;
        short8 kf = *(const short8*)&Ksm[krow*64 + (((kh*4 + fg) ^ (krow & 7)) * 8)];
        sacc[0][n] = MFMA16(qf[0][kh], kf, sacc[0][n]);
        sacc[1][n] = MFMA16(qf[1][kh], kf, sacc[1][n]);
      }
    }

    #pragma unroll
    for (int m = 0; m < 2; m++) {
      float pm[4];
      #pragma unroll
      for (int r = 0; r < 4; r++)
        pm[r] = fmaxf(fmaxf(sacc[m][0][r], sacc[m][1][r]),
                      fmaxf(sacc[m][2][r], sacc[m][3][r]));
      #pragma unroll
      for (int msk = 1; msk < 16; msk <<= 1)
        #pragma unroll
        for (int r = 0; r < 4; r++) pm[r] = fmaxf(pm[r], __shfl_xor(pm[r], msk));
      float corr[4];
      #pragma unroll
      for (int r = 0; r < 4; r++) {
        float mn = fmaxf(mrow[m][r], pm[r]);
        corr[r] = __expf(mrow[m][r] - mn);
        mrow[m][r] = mn;
      }
      float psum[4] = {0.f, 0.f, 0.f, 0.f};
      #pragma unroll
      for (int n = 0; n < 4; n++)
        #pragma unroll
        for (int r = 0; r < 4; r++) {
          float p = __expf(sacc[m][n][r] - mrow[m][r]);
          sacc[m][n][r] = p;
          psum[r] += p;
        }
      #pragma unroll
      for (int msk = 1; msk < 16; msk <<= 1)
        #pragma unroll
        for (int r = 0; r < 4; r++) psum[r] += __shfl_xor(psum[r], msk);
      #pragma unroll
      for (int r = 0; r < 4; r++) lrow[m][r] = lrow[m][r] * corr[r] + psum[r];
      #pragma unroll
      for (int d16 = 0; d16 < 4; d16++)
        #pragma unroll
        for (int r = 0; r < 4; r++) oacc[m][d16][r] *= corr[r];
      #pragma unroll
      for (int n = 0; n < 4; n++)
        #pragma unroll
        for (int r = 0; r < 4; r++)
          plds[wid][m*16 + fg*4 + r][n*16 + fr] = f2bf(sacc[m][n][r]);
    }

    short8 pf[2][2];
    #pragma unroll
    for (int m = 0; m < 2; m++)
      #pragma unroll
      for (int kh = 0; kh < 2; kh++)
        pf[m][kh] = *(const short8*)&plds[wid][m*16 + fr][kh*32 + fg*8];

    #pragma unroll
    for (int d16 = 0; d16 < 4; d16++) {
      #pragma unroll
      for (int kh = 0; kh < 2; kh++) {
        const int vrow = d16*16 + fr;
        short8 vf = *(const short8*)&Vsm[vrow*64 + (((kh*4 + fg) ^ (vrow & 7)) * 8)];
        oacc[0][d16] = MFMA16(pf[0][kh], vf, oacc[0][d16]);
        oacc[1][d16] = MFMA16(pf[1][kh], vf, oacc[1][d16]);
      }
    }
  }

  #pragma unroll
  for (int m = 0; m < 2; m++) {
    float inv[4];
    #pragma unroll
    for (int r = 0; r < 4; r++) inv[r] = 1.0f / lrow[m][r];
    #pragma unroll
    for (int d16 = 0; d16 < 4; d16++) {
      #pragma unroll
      for (int r = 0; r < 4; r++) {
        const int qrow = q0 + m*16 + fg*4 + r;
        const int col = h*64 + d16*16 + fr;
        out[(size_t)(b * 1024 + qrow) * 1024 + col] = f2bf(oacc[m][d16][r] * inv[r]);
      }
    }
  }
}

// ---------------- host launch ----------------
extern "C" void kernel_launch(void* const* d_in, const int* in_sizes, int n_in,
                              void* d_out, int out_size, void* d_ws, size_t ws_size,
                              hipStream_t stream) {
  const float* x      = (const float*)d_in[0];
  const float* ln1_g  = (const float*)d_in[1];
  const float* ln1_b  = (const float*)d_in[2];
  const float* qkv_w  = (const float*)d_in[3];
  const float* qkv_b  = (const float*)d_in[4];
  const float* proj_w = (const float*)d_in[5];
  const float* proj_b = (const float*)d_in[6];
  const float* ls1_g  = (const float*)d_in[7];
  const float* ln2_g  = (const float*)d_in[8];
  const float* ln2_b  = (const float*)d_in[9];
  const float* fc1_w  = (const float*)d_in[10];
  const float* fc1_b  = (const float*)d_in[11];
  const float* fc2_w  = (const float*)d_in[12];
  const float* fc2_b  = (const float*)d_in[13];
  const float* ls2_g  = (const float*)d_in[14];

  char* w = (char*)d_ws;
  unsigned short* wqkvT  = (unsigned short*)(w + 0);                    //  6,291,456
  unsigned short* wprojT = (unsigned short*)(w + 6291456);              //  2,097,152
  unsigned short* wfc1T  = (unsigned short*)(w + 8388608);              //  8,388,608
  unsigned short* wfc2T  = (unsigned short*)(w + 16777216);             //  8,388,608
  float*          x1     = (float*)(w + 25165824);                      // 67,108,864
  unsigned short* h1     = (unsigned short*)(w + 92274688);             // 33,554,432 (reused as h2)
  unsigned short* qkbuf  = (unsigned short*)(w + 125829120);            // 67,108,864 [16384][2048]
  unsigned short* vtbuf  = (unsigned short*)(w + 192937984);            // 33,554,432 [256][64][1024]
  unsigned short* attno  = (unsigned short*)(w + 226492416);            // 33,554,432
  unsigned short* h3     = (unsigned short*)(w + 125829120);            // 134,217,728 (overlays qk+vT)

  dim3 tb32(32, 8);
  k_transpose_cast<<<dim3(3072/32, 1024/32), tb32, 0, stream>>>(qkv_w,  wqkvT, 1024, 3072);
  k_transpose_cast<<<dim3(1024/32, 1024/32), tb32, 0, stream>>>(proj_w, wprojT, 1024, 1024);
  k_transpose_cast<<<dim3(4096/32, 1024/32), tb32, 0, stream>>>(fc1_w,  wfc1T, 1024, 4096);
  k_transpose_cast<<<dim3(1024/32, 4096/32), tb32, 0, stream>>>(fc2_w,  wfc2T, 4096, 1024);

  // LN1
  k_layernorm<<<16384, 256, 0, stream>>>(x, ln1_g, ln1_b, h1);
  // QKV = h1 @ qkv_w + qkv_b ; Q,K -> qkbuf, V -> vtbuf transposed
  k_gemm256<0><<<64*12, 512, 0, stream>>>(h1, wqkvT, qkv_b, nullptr, nullptr,
                                          qkbuf, vtbuf, 16384, 3072, 1024, 12);
  // attention
  k_attn<<<dim3(4, 256), 512, 0, stream>>>(qkbuf, vtbuf, attno);
  // x1 = x + (attn @ proj_w + proj_b) * ls1_g
  k_gemm256<2><<<64*4, 512, 0, stream>>>(attno, wprojT, proj_b, x, ls1_g,
                                         x1, nullptr, 16384, 1024, 1024, 4);
  // LN2
  k_layernorm<<<16384, 256, 0, stream>>>(x1, ln2_g, ln2_b, h1);
  // h3 = gelu(h2 @ fc1_w + fc1_b)
  k_gemm256<1><<<64*16, 512, 0, stream>>>(h1, wfc1T, fc1_b, nullptr, nullptr,
                                          h3, nullptr, 16384, 4096, 1024, 16);
  // out = x1 + (h3 @ fc2_w + fc2_b) * ls2_g
  k_gemm256<2><<<64*4, 512, 0, stream>>>(h3, wfc2T, fc2_b, x1, ls2_g,
                                         (float*)d_out, nullptr, 16384, 1024, 4096, 4);
}

// Round 6
// 1012.278 us; speedup vs baseline: 5.8180x; 1.0953x over previous
//
#include <hip/hip_runtime.h>
#include <hip/hip_bf16.h>
#include <math.h>

typedef __attribute__((ext_vector_type(8))) short short8;
typedef __attribute__((ext_vector_type(4))) float f32x4;

#define MFMA16(a,b,c) __builtin_amdgcn_mfma_f32_16x16x32_bf16((a),(b),(c),0,0,0)

__device__ __forceinline__ unsigned short f2bf(float f){
  unsigned int u = __builtin_bit_cast(unsigned int, f);
  u += 0x7fffu + ((u >> 16) & 1u);
  return (unsigned short)(u >> 16);
}

__device__ __forceinline__ void gload16(const void* g, void* lds){
  __builtin_amdgcn_global_load_lds(
      (const __attribute__((address_space(1))) unsigned int*)g,
      (__attribute__((address_space(3))) unsigned int*)lds, 16, 0, 0);
}

// ---------------- weight transpose + cast: in [K][N] f32 -> out [N][K] bf16 ----------------
__global__ __launch_bounds__(256) void k_transpose_cast(const float* __restrict__ in,
    unsigned short* __restrict__ out, int K, int N)
{
  __shared__ unsigned short tile[32][33];
  const int tx = threadIdx.x, ty = threadIdx.y;
  const int n0 = blockIdx.x * 32, k0 = blockIdx.y * 32;
  #pragma unroll
  for (int i = 0; i < 4; i++) {
    int k = k0 + ty + i*8;
    tile[ty + i*8][tx] = f2bf(in[(size_t)k * N + n0 + tx]);
  }
  __syncthreads();
  #pragma unroll
  for (int i = 0; i < 4; i++) {
    int n = n0 + ty + i*8;
    out[(size_t)n * K + k0 + tx] = tile[tx][ty + i*8];
  }
}

// ---------------- layernorm: x [rows][1024] f32 -> out bf16 ----------------
__global__ __launch_bounds__(256) void k_layernorm(const float* __restrict__ x,
    const float* __restrict__ g, const float* __restrict__ b,
    unsigned short* __restrict__ out)
{
  const int row = blockIdx.x;
  const int t = threadIdx.x;
  const float4 v = ((const float4*)(x + (size_t)row * 1024))[t];
  float s  = v.x + v.y + v.z + v.w;
  float s2 = v.x*v.x + v.y*v.y + v.z*v.z + v.w*v.w;
  #pragma unroll
  for (int m = 1; m < 64; m <<= 1) {
    s  += __shfl_xor(s,  m);
    s2 += __shfl_xor(s2, m);
  }
  __shared__ float red[2][4];
  const int wid = t >> 6, lane = t & 63;
  if (lane == 0) { red[0][wid] = s; red[1][wid] = s2; }
  __syncthreads();
  s  = red[0][0] + red[0][1] + red[0][2] + red[0][3];
  s2 = red[1][0] + red[1][1] + red[1][2] + red[1][3];
  const float mu = s * (1.0f / 1024.0f);
  const float var = s2 * (1.0f / 1024.0f) - mu * mu;
  const float rstd = rsqrtf(var + 1e-6f);
  const float4 gv = ((const float4*)g)[t];
  const float4 bv = ((const float4*)b)[t];
  ushort4 o;
  o.x = f2bf((v.x - mu) * rstd * gv.x + bv.x);
  o.y = f2bf((v.y - mu) * rstd * gv.y + bv.y);
  o.z = f2bf((v.z - mu) * rstd * gv.z + bv.z);
  o.w = f2bf((v.w - mu) * rstd * gv.w + bv.w);
  ((ushort4*)(out + (size_t)row * 1024))[t] = o;
}

// ---------------- 256x256 MFMA GEMM — 8-phase interleaved schedule (T2+T3+T4+T5, XCD swizzle) --
// C[M][N] = A[M][K](bf16) * Bt[N][K]^T(bf16) + epilogue
// EPI 0: QKV mode: bn<8 -> qk buffer (stride 2048) bf16; bn>=8 -> vT[b][h][d][n] bf16
// EPI 1: out bf16 = gelu_exact(acc + bias)
// EPI 2: out f32  = resid + (acc + bias) * lsg
//
// Staging units per 256x64 K-tile (1 gload_lds/thread each, 8 total):
//   u0:A r[0,64) u1:A r[128,192) u2:A r[64,128) u3:A r[192,256)
//   u4:B r[0,64) u5:B r[64,128)  u6:B r[128,192) u7:B r[192,256)
// Retirement: A-mh0 regions (u0,u1 rows) free after ph2; A-mh1+B after ph4 (sym. ph6/ph8).
// Steady-state issue: ph1:[P.u2,P.u3] ph2:[P.u4,P.u5] ph3:[P.u6,Q.u0] ph4:[P.u7,Q.u1]
//                     ph5:[Q.u2,Q.u3] ph6:[Q.u4,Q.u5] ph7:[Q.u6,R.u0] ph8:[Q.u7,R.u1]
// (P=T+1->buf1, Q=T+2->buf0, R=T+3->buf1). vmcnt(3) at ph1/ph5 => 3 half-tiles in flight.
template<int EPI>
__global__ __launch_bounds__(512, 2) void k_gemm256(
    const unsigned short* __restrict__ A,
    const unsigned short* __restrict__ Bt,
    const float* __restrict__ bias,
    const float* __restrict__ resid,
    const float* __restrict__ lsg,
    void* __restrict__ outp,
    unsigned short* __restrict__ vtp,
    int M, int N, int K, int nbn)
{
  __shared__ __align__(16) char smem[131072];  // A: 2x32KB at 0, B: 2x32KB at 64KB
  const unsigned short* Ash = (const unsigned short*)smem;
  const unsigned short* Bsh = Ash + 32768;

  // XCD-chunked bijective swizzle
  const int bid = blockIdx.x;
  const int mrows = (gridDim.x >> 3) / nbn;
  const int xcd = bid & 7, l = bid >> 3;
  const int bm = xcd * mrows + (l % mrows);
  const int bn = l / mrows;

  const int t = threadIdx.x, lane = t & 63;
  const int wid = t >> 6, wm = wid >> 2, wn = wid & 3;
  const int fr = lane & 15, fg = lane >> 4;

  // staging addressing (chunk-XOR pre-swizzled source, linear LDS dest — rule #21)
  const int rowL = t >> 3;
  const int cs8 = ((t & 7) ^ (rowL & 7)) * 8;
  const size_t aBase = ((size_t)bm * 256 + rowL) * K + cs8;
  const size_t bBase = ((size_t)bn * 256 + rowL) * K + cs8;

#define STG_A(rowb, bb, X) gload16(A  + aBase + (size_t)(rowb)*K + (size_t)(X)*64, \
                                   smem + (bb)*32768 + (rowb)*128 + t*16)
#define STG_B(rowb, bb, X) gload16(Bt + bBase + (size_t)(rowb)*K + (size_t)(X)*64, \
                                   smem + 65536 + (bb)*32768 + (rowb)*128 + t*16)

#define RD_A(mh, bb) \
  _Pragma("unroll") \
  for (int m_ = 0; m_ < 4; m_++) { \
    const int row_ = wm*128 + (mh)*64 + m_*16 + fr; \
    const unsigned short* p_ = Ash + (bb)*16384 + row_*64; \
    af[m_*2+0] = *(const short8*)&p_[((fg)     ^ (row_&7))*8]; \
    af[m_*2+1] = *(const short8*)&p_[((4+fg)   ^ (row_&7))*8]; \
  }

#define RD_B(nh, bb) \
  _Pragma("unroll") \
  for (int n_ = 0; n_ < 2; n_++) { \
    const int row_ = wn*64 + (nh)*32 + n_*16 + fr; \
    const unsigned short* p_ = Bsh + (bb)*16384 + row_*64; \
    bf[n_*2+0] = *(const short8*)&p_[((fg)     ^ (row_&7))*8]; \
    bf[n_*2+1] = *(const short8*)&p_[((4+fg)   ^ (row_&7))*8]; \
  }

#define MMAQ(mh, nh) \
  __builtin_amdgcn_s_setprio(1); \
  _Pragma("unroll") \
  for (int kk_ = 0; kk_ < 2; kk_++) \
    _Pragma("unroll") \
    for (int m_ = 0; m_ < 4; m_++) \
      _Pragma("unroll") \
      for (int n_ = 0; n_ < 2; n_++) \
        acc[(mh)*4+m_][(nh)*2+n_] = \
            MFMA16(af[m_*2+kk_], bf[n_*2+kk_], acc[(mh)*4+m_][(nh)*2+n_]); \
  __builtin_amdgcn_s_setprio(0);

#define BAR asm volatile("s_barrier" ::: "memory")

  f32x4 acc[8][4] = {};
  short8 af[8], bf[4];
  const int NT = K >> 6;

  // prologue: T0 fully + T1.u0,u1, in steady-state order
  STG_A(0,   0, 0); STG_A(128, 0, 0);
  STG_A(64,  0, 0); STG_A(192, 0, 0);
  STG_B(0,   0, 0); STG_B(64,  0, 0);
  STG_B(128, 0, 0);
  STG_A(0,   1, 1);
  STG_B(192, 0, 0);
  STG_A(128, 1, 1);

  for (int it2 = 0; it2 < (NT >> 1); ++it2) {
    const int T = it2 * 2;
    const bool more = (T + 2 < NT);
    // ---- ph1: tile T (buf0) quadrant (0,0) ----
    STG_A(64, 1, T+1); STG_A(192, 1, T+1);
    asm volatile("s_waitcnt vmcnt(3)" ::: "memory");
    BAR;
    RD_A(0, 0); RD_B(0, 0);
    MMAQ(0, 0);
    BAR;
    // ---- ph2: (0,1) ----
    STG_B(0, 1, T+1); STG_B(64, 1, T+1);
    RD_B(1, 0);
    BAR;
    MMAQ(0, 1);
    BAR;
    // ---- ph3: (1,0) ----
    STG_B(128, 1, T+1);
    if (more) STG_A(0, 0, T+2);
    RD_A(1, 0); RD_B(0, 0);
    BAR;
    MMAQ(1, 0);
    BAR;
    // ---- ph4: (1,1) ----
    STG_B(192, 1, T+1);
    if (more) STG_A(128, 0, T+2);
    RD_B(1, 0);
    BAR;
    MMAQ(1, 1);
    BAR;
    // ---- ph5: tile T+1 (buf1) quadrant (0,0) ----
    if (more) {
      STG_A(64, 0, T+2); STG_A(192, 0, T+2);
      asm volatile("s_waitcnt vmcnt(3)" ::: "memory");
    } else {
      asm volatile("s_waitcnt vmcnt(0)" ::: "memory");
    }
    BAR;
    RD_A(0, 1); RD_B(0, 1);
    MMAQ(0, 0);
    BAR;
    // ---- ph6: (0,1) ----
    if (more) { STG_B(0, 0, T+2); STG_B(64, 0, T+2); }
    RD_B(1, 1);
    BAR;
    MMAQ(0, 1);
    BAR;
    // ---- ph7: (1,0) ----
    if (more) { STG_B(128, 0, T+2); STG_A(0, 1, T+3); }
    RD_A(1, 1); RD_B(0, 1);
    BAR;
    MMAQ(1, 0);
    BAR;
    // ---- ph8: (1,1) ----
    if (more) { STG_B(192, 0, T+2); STG_A(128, 1, T+3); }
    RD_B(1, 1);
    BAR;
    MMAQ(1, 1);
    BAR;
  }

  // ---- epilogue: direct stores (round-3 proven) ----
  const int row0 = bm * 256 + wm * 128 + fg * 4;
  const int col0 = bn * 256 + wn * 64 + fr;
  #pragma unroll
  for (int n = 0; n < 4; n++) {
    const int col = col0 + n * 16;
    const float bcol = bias[col];
    float lscale = 0.f;
    if (EPI == 2) lscale = lsg[col];
    #pragma unroll
    for (int m = 0; m < 8; m++) {
      #pragma unroll
      for (int r = 0; r < 4; r++) {
        const int row = row0 + m * 16 + r;
        float v = acc[m][n][r] + bcol;
        if (EPI == 0) {
          if (bn < 8) {
            ((unsigned short*)outp)[(size_t)row * 2048 + col] = f2bf(v);
          } else {
            const int d = col - 2048, hh = d >> 6, dd = d & 63;
            const int bb = row >> 10, nn = row & 1023;
            vtp[(((size_t)bb * 16 + hh) * 64 + dd) * 1024 + nn] = f2bf(v);
          }
        } else if (EPI == 1) {
          v = 0.5f * v * (1.0f + erff(v * 0.70710678118654752f));
          ((unsigned short*)outp)[(size_t)row * N + col] = f2bf(v);
        } else {
          ((float*)outp)[(size_t)row * N + col] =
              resid[(size_t)row * N + col] + v * lscale;
        }
      }
    }
  }
#undef STG_A
#undef STG_B
#undef RD_A
#undef RD_B
#undef MMAQ
#undef BAR
}

// ---------------- flash attention (no 1/sqrt(d) scale, faithful to ref) ----------------
// qk: [16384][2048] bf16 ; vT: [b][h][64 d][1024 n] bf16 ; out: [16384][1024] bf16
__global__ __launch_bounds__(512) void k_attn(const unsigned short* __restrict__ qk,
                                              const unsigned short* __restrict__ vT,
                                              unsigned short* __restrict__ out)
{
  const int qt = blockIdx.x;       // 0..3  (q tile of 256 rows)
  const int bh = blockIdx.y;       // 0..255
  const int b = bh >> 4, h = bh & 15;
  const int t = threadIdx.x, lane = t & 63, wid = t >> 6;
  const int fr = lane & 15, fg = lane >> 4;
  const int q0 = qt * 256 + wid * 32;

  __shared__ __align__(16) unsigned short Ksm[64 * 64];
  __shared__ __align__(16) unsigned short Vsm[64 * 64];
  __shared__ __align__(16) unsigned short plds[8][32][72];

  const size_t qbase = (size_t)b * 1024 * 2048 + (size_t)h * 64;
  const size_t kbase = qbase + 1024;
  const size_t vbase = (size_t)bh * 64 * 1024;

  short8 qf[2][2];
  #pragma unroll
  for (int m = 0; m < 2; m++)
    #pragma unroll
    for (int kh = 0; kh < 2; kh++)
      qf[m][kh] = *(const short8*)(qk + qbase + (size_t)(q0 + m*16 + fr) * 2048
                                   + kh*32 + fg*8);

  f32x4 oacc[2][4] = {};
  float mrow[2][4], lrow[2][4];
  #pragma unroll
  for (int m = 0; m < 2; m++)
    #pragma unroll
    for (int r = 0; r < 4; r++) { mrow[m][r] = -1e30f; lrow[m][r] = 0.f; }

  const int srow = t >> 3, sc = t & 7;
  const int scs = sc ^ (srow & 7);

  for (int kv0 = 0; kv0 < 1024; kv0 += 64) {
    __syncthreads();
    gload16(qk + kbase + (size_t)(kv0 + srow) * 2048 + scs*8, (char*)Ksm + t*16);
    gload16(vT + vbase + (size_t)srow * 1024 + kv0 + scs*8,   (char*)Vsm + t*16);
    __syncthreads();

    f32x4 sacc[2][4] = {};
    #pragma unroll
    for (int n = 0; n < 4; n++) {
      #pragma unroll
      for (int kh = 0; kh < 2; kh++) {
        const int krow = n*16 + fr;
        short8 kf = *(const short8*)&Ksm[krow*64 + (((kh*4 + fg) ^ (krow & 7)) * 8)];
        sacc[0][n] = MFMA16(qf[0][kh], kf, sacc[0][n]);
        sacc[1][n] = MFMA16(qf[1][kh], kf, sacc[1][n]);
      }
    }

    #pragma unroll
    for (int m = 0; m < 2; m++) {
      float pm[4];
      #pragma unroll
      for (int r = 0; r < 4; r++)
        pm[r] = fmaxf(fmaxf(sacc[m][0][r], sacc[m][1][r]),
                      fmaxf(sacc[m][2][r], sacc[m][3][r]));
      #pragma unroll
      for (int msk = 1; msk < 16; msk <<= 1)
        #pragma unroll
        for (int r = 0; r < 4; r++) pm[r] = fmaxf(pm[r], __shfl_xor(pm[r], msk));
      float corr[4];
      #pragma unroll
      for (int r = 0; r < 4; r++) {
        float mn = fmaxf(mrow[m][r], pm[r]);
        corr[r] = __expf(mrow[m][r] - mn);
        mrow[m][r] = mn;
      }
      float psum[4] = {0.f, 0.f, 0.f, 0.f};
      #pragma unroll
      for (int n = 0; n < 4; n++)
        #pragma unroll
        for (int r = 0; r < 4; r++) {
          float p = __expf(sacc[m][n][r] - mrow[m][r]);
          sacc[m][n][r] = p;
          psum[r] += p;
        }
      #pragma unroll
      for (int msk = 1; msk < 16; msk <<= 1)
        #pragma unroll
        for (int r = 0; r < 4; r++) psum[r] += __shfl_xor(psum[r], msk);
      #pragma unroll
      for (int r = 0; r < 4; r++) lrow[m][r] = lrow[m][r] * corr[r] + psum[r];
      #pragma unroll
      for (int d16 = 0; d16 < 4; d16++)
        #pragma unroll
        for (int r = 0; r < 4; r++) oacc[m][d16][r] *= corr[r];
      #pragma unroll
      for (int n = 0; n < 4; n++)
        #pragma unroll
        for (int r = 0; r < 4; r++)
          plds[wid][m*16 + fg*4 + r][n*16 + fr] = f2bf(sacc[m][n][r]);
    }

    short8 pf[2][2];
    #pragma unroll
    for (int m = 0; m < 2; m++)
      #pragma unroll
      for (int kh = 0; kh < 2; kh++)
        pf[m][kh] = *(const short8*)&plds[wid][m*16 + fr][kh*32 + fg*8];

    #pragma unroll
    for (int d16 = 0; d16 < 4; d16++) {
      #pragma unroll
      for (int kh = 0; kh < 2; kh++) {
        const int vrow = d16*16 + fr;
        short8 vf = *(const short8*)&Vsm[vrow*64 + (((kh*4 + fg) ^ (vrow & 7)) * 8)];
        oacc[0][d16] = MFMA16(pf[0][kh], vf, oacc[0][d16]);
        oacc[1][d16] = MFMA16(pf[1][kh], vf, oacc[1][d16]);
      }
    }
  }

  #pragma unroll
  for (int m = 0; m < 2; m++) {
    float inv[4];
    #pragma unroll
    for (int r = 0; r < 4; r++) inv[r] = 1.0f / lrow[m][r];
    #pragma unroll
    for (int d16 = 0; d16 < 4; d16++) {
      #pragma unroll
      for (int r = 0; r < 4; r++) {
        const int qrow = q0 + m*16 + fg*4 + r;
        const int col = h*64 + d16*16 + fr;
        out[(size_t)(b * 1024 + qrow) * 1024 + col] = f2bf(oacc[m][d16][r] * inv[r]);
      }
    }
  }
}

// ---------------- host launch ----------------
extern "C" void kernel_launch(void* const* d_in, const int* in_sizes, int n_in,
                              void* d_out, int out_size, void* d_ws, size_t ws_size,
                              hipStream_t stream) {
  const float* x      = (const float*)d_in[0];
  const float* ln1_g  = (const float*)d_in[1];
  const float* ln1_b  = (const float*)d_in[2];
  const float* qkv_w  = (const float*)d_in[3];
  const float* qkv_b  = (const float*)d_in[4];
  const float* proj_w = (const float*)d_in[5];
  const float* proj_b = (const float*)d_in[6];
  const float* ls1_g  = (const float*)d_in[7];
  const float* ln2_g  = (const float*)d_in[8];
  const float* ln2_b  = (const float*)d_in[9];
  const float* fc1_w  = (const float*)d_in[10];
  const float* fc1_b  = (const float*)d_in[11];
  const float* fc2_w  = (const float*)d_in[12];
  const float* fc2_b  = (const float*)d_in[13];
  const float* ls2_g  = (const float*)d_in[14];

  char* w = (char*)d_ws;
  unsigned short* wqkvT  = (unsigned short*)(w + 0);                    //  6,291,456
  unsigned short* wprojT = (unsigned short*)(w + 6291456);              //  2,097,152
  unsigned short* wfc1T  = (unsigned short*)(w + 8388608);              //  8,388,608
  unsigned short* wfc2T  = (unsigned short*)(w + 16777216);             //  8,388,608
  float*          x1     = (float*)(w + 25165824);                      // 67,108,864
  unsigned short* h1     = (unsigned short*)(w + 92274688);             // 33,554,432 (reused as h2)
  unsigned short* qkbuf  = (unsigned short*)(w + 125829120);            // 67,108,864 [16384][2048]
  unsigned short* vtbuf  = (unsigned short*)(w + 192937984);            // 33,554,432 [256][64][1024]
  unsigned short* attno  = (unsigned short*)(w + 226492416);            // 33,554,432
  unsigned short* h3     = (unsigned short*)(w + 125829120);            // 134,217,728 (overlays qk+vT)

  dim3 tb32(32, 8);
  k_transpose_cast<<<dim3(3072/32, 1024/32), tb32, 0, stream>>>(qkv_w,  wqkvT, 1024, 3072);
  k_transpose_cast<<<dim3(1024/32, 1024/32), tb32, 0, stream>>>(proj_w, wprojT, 1024, 1024);
  k_transpose_cast<<<dim3(4096/32, 1024/32), tb32, 0, stream>>>(fc1_w,  wfc1T, 1024, 4096);
  k_transpose_cast<<<dim3(1024/32, 4096/32), tb32, 0, stream>>>(fc2_w,  wfc2T, 4096, 1024);

  // LN1
  k_layernorm<<<16384, 256, 0, stream>>>(x, ln1_g, ln1_b, h1);
  // QKV = h1 @ qkv_w + qkv_b ; Q,K -> qkbuf, V -> vtbuf transposed
  k_gemm256<0><<<64*12, 512, 0, stream>>>(h1, wqkvT, qkv_b, nullptr, nullptr,
                                          qkbuf, vtbuf, 16384, 3072, 1024, 12);
  // attention
  k_attn<<<dim3(4, 256), 512, 0, stream>>>(qkbuf, vtbuf, attno);
  // x1 = x + (attn @ proj_w + proj_b) * ls1_g
  k_gemm256<2><<<64*4, 512, 0, stream>>>(attno, wprojT, proj_b, x, ls1_g,
                                         x1, nullptr, 16384, 1024, 1024, 4);
  // LN2
  k_layernorm<<<16384, 256, 0, stream>>>(x1, ln2_g, ln2_b, h1);
  // h3 = gelu(h2 @ fc1_w + fc1_b)
  k_gemm256<1><<<64*16, 512, 0, stream>>>(h1, wfc1T, fc1_b, nullptr, nullptr,
                                          h3, nullptr, 16384, 4096, 1024, 16);
  // out = x1 + (h3 @ fc2_w + fc2_b) * ls2_g
  k_gemm256<2><<<64*4, 512, 0, stream>>>(h3, wfc2T, fc2_b, x1, ls2_g,
                                         (float*)d_out, nullptr, 16384, 1024, 4096, 4);
}

// Round 7
// 834.026 us; speedup vs baseline: 7.0615x; 1.2137x over previous
//
#include <hip/hip_runtime.h>
#include <hip/hip_bf16.h>
#include <math.h>

typedef __attribute__((ext_vector_type(8))) short short8;
typedef __attribute__((ext_vector_type(4))) float f32x4;

#define MFMA16(a,b,c) __builtin_amdgcn_mfma_f32_16x16x32_bf16((a),(b),(c),0,0,0)

__device__ __forceinline__ unsigned short f2bf(float f){
  unsigned int u = __builtin_bit_cast(unsigned int, f);
  u += 0x7fffu + ((u >> 16) & 1u);
  return (unsigned short)(u >> 16);
}

__device__ __forceinline__ void gload16(const void* g, void* lds){
  __builtin_amdgcn_global_load_lds(
      (const __attribute__((address_space(1))) unsigned int*)g,
      (__attribute__((address_space(3))) unsigned int*)lds, 16, 0, 0);
}

// ---------------- weight transpose + cast: in [K][N] f32 -> out [N][K] bf16 ----------------
__global__ __launch_bounds__(256) void k_transpose_cast(const float* __restrict__ in,
    unsigned short* __restrict__ out, int K, int N)
{
  __shared__ unsigned short tile[32][33];
  const int tx = threadIdx.x, ty = threadIdx.y;
  const int n0 = blockIdx.x * 32, k0 = blockIdx.y * 32;
  #pragma unroll
  for (int i = 0; i < 4; i++) {
    int k = k0 + ty + i*8;
    tile[ty + i*8][tx] = f2bf(in[(size_t)k * N + n0 + tx]);
  }
  __syncthreads();
  #pragma unroll
  for (int i = 0; i < 4; i++) {
    int n = n0 + ty + i*8;
    out[(size_t)n * K + k0 + tx] = tile[tx][ty + i*8];
  }
}

// ---------------- layernorm: x [rows][1024] f32 -> out bf16 ----------------
__global__ __launch_bounds__(256) void k_layernorm(const float* __restrict__ x,
    const float* __restrict__ g, const float* __restrict__ b,
    unsigned short* __restrict__ out)
{
  const int row = blockIdx.x;
  const int t = threadIdx.x;
  const float4 v = ((const float4*)(x + (size_t)row * 1024))[t];
  float s  = v.x + v.y + v.z + v.w;
  float s2 = v.x*v.x + v.y*v.y + v.z*v.z + v.w*v.w;
  #pragma unroll
  for (int m = 1; m < 64; m <<= 1) {
    s  += __shfl_xor(s,  m);
    s2 += __shfl_xor(s2, m);
  }
  __shared__ float red[2][4];
  const int wid = t >> 6, lane = t & 63;
  if (lane == 0) { red[0][wid] = s; red[1][wid] = s2; }
  __syncthreads();
  s  = red[0][0] + red[0][1] + red[0][2] + red[0][3];
  s2 = red[1][0] + red[1][1] + red[1][2] + red[1][3];
  const float mu = s * (1.0f / 1024.0f);
  const float var = s2 * (1.0f / 1024.0f) - mu * mu;
  const float rstd = rsqrtf(var + 1e-6f);
  const float4 gv = ((const float4*)g)[t];
  const float4 bv = ((const float4*)b)[t];
  ushort4 o;
  o.x = f2bf((v.x - mu) * rstd * gv.x + bv.x);
  o.y = f2bf((v.y - mu) * rstd * gv.y + bv.y);
  o.z = f2bf((v.z - mu) * rstd * gv.z + bv.z);
  o.w = f2bf((v.w - mu) * rstd * gv.w + bv.w);
  ((ushort4*)(out + (size_t)row * 1024))[t] = o;
}

// ---------------- 256x256 MFMA GEMM — 4-phase min-LDS-read schedule ----------------
// C[M][N] = A[M][K](bf16) * Bt[N][K]^T(bf16) + epilogue
// EPI 0: QKV mode: bn<8 -> qk buffer (stride 2048) bf16; bn>=8 -> vT[b][h][d][n] bf16
// EPI 1: out bf16 = gelu(acc + bias)  (sigmoid-form tanh approx)
// EPI 2: out f32  = resid + (acc + bias) * lsg
//
// Per 2 K-tiles (buf0=2j, buf1=2j+1), 4 phases, 24 ds_read_b128/wave/K-tile (minimum):
//  phA0: STG B(2j+1->buf1); vmcnt(8); BAR; RD af0+bf (buf0,16 rd); MFMA mh0 x32; BAR
//  phB0: RD af1 (buf0,8 rd); STG A(2j+2->buf0); BAR; MFMA mh1 x32; BAR
//  phA1: STG B(2j+2->buf0); vmcnt(8|0); BAR; RD af0+bf (buf1); MFMA mh0; BAR
//  phB1: RD af1 (buf1); STG A(2j+3->buf1); BAR; MFMA mh1; BAR
// vmcnt(8): 8 loads/thread in flight (one full tile of prefetch); in-order retire
// certifies the tile being read. Reads precede staging in phB (race-window close).
template<int EPI>
__global__ __launch_bounds__(512, 2) void k_gemm256(
    const unsigned short* __restrict__ A,
    const unsigned short* __restrict__ Bt,
    const float* __restrict__ bias,
    const float* __restrict__ resid,
    const float* __restrict__ lsg,
    void* __restrict__ outp,
    unsigned short* __restrict__ vtp,
    int M, int N, int K, int nbn)
{
  __shared__ __align__(16) char smem[131072];  // A: 2x32KB at 0, B: 2x32KB at 64KB

  // XCD-chunked bijective swizzle
  const int bid = blockIdx.x;
  const int mrows = (gridDim.x >> 3) / nbn;
  const int xcd = bid & 7, l = bid >> 3;
  const int bm = xcd * mrows + (l % mrows);
  const int bn = l / mrows;

  const int t = threadIdx.x, lane = t & 63;
  const int wid = t >> 6, wm = wid >> 2, wn = wid & 3;
  const int fr = lane & 15, fg = lane >> 4;

  // staging addressing (chunk-XOR pre-swizzled source, linear LDS dest — rule #21)
  const int rowL = t >> 3;
  const int cs8 = ((t & 7) ^ (rowL & 7)) * 8;
  const size_t aBase = ((size_t)bm * 256 + rowL) * K + cs8;
  const size_t bBase = ((size_t)bn * 256 + rowL) * K + cs8;

#define STG_A(rowb, bb, X) gload16(A  + aBase + (size_t)(rowb)*K + (size_t)(X)*64, \
                                   smem + (bb)*32768 + (rowb)*128 + t*16)
#define STG_B(rowb, bb, X) gload16(Bt + bBase + (size_t)(rowb)*K + (size_t)(X)*64, \
                                   smem + 65536 + (bb)*32768 + (rowb)*128 + t*16)
#define STG_A4(bb, X) { STG_A(0,bb,X); STG_A(64,bb,X); STG_A(128,bb,X); STG_A(192,bb,X); }
#define STG_B4(bb, X) { STG_B(0,bb,X); STG_B(64,bb,X); STG_B(128,bb,X); STG_B(192,bb,X); }

#define RD_AF(mh, bb) \
  _Pragma("unroll") \
  for (int m_ = 0; m_ < 4; m_++) { \
    const int row_ = wm*128 + (mh)*64 + m_*16 + fr; \
    const unsigned short* p_ = (const unsigned short*)smem + (bb)*16384 + row_*64; \
    af[m_*2+0] = *(const short8*)&p_[((fg)   ^ (row_&7))*8]; \
    af[m_*2+1] = *(const short8*)&p_[((4+fg) ^ (row_&7))*8]; \
  }

#define RD_BF(bb) \
  _Pragma("unroll") \
  for (int n_ = 0; n_ < 4; n_++) { \
    const int row_ = wn*64 + n_*16 + fr; \
    const unsigned short* p_ = (const unsigned short*)(smem + 65536) + (bb)*16384 + row_*64; \
    bfv[n_*2+0] = *(const short8*)&p_[((fg)   ^ (row_&7))*8]; \
    bfv[n_*2+1] = *(const short8*)&p_[((4+fg) ^ (row_&7))*8]; \
  }

#define MMAH(mh) \
  __builtin_amdgcn_s_setprio(1); \
  _Pragma("unroll") \
  for (int kk_ = 0; kk_ < 2; kk_++) \
    _Pragma("unroll") \
    for (int m_ = 0; m_ < 4; m_++) \
      _Pragma("unroll") \
      for (int n_ = 0; n_ < 4; n_++) \
        acc[(mh)*4+m_][n_] = MFMA16(af[m_*2+kk_], bfv[n_*2+kk_], acc[(mh)*4+m_][n_]); \
  __builtin_amdgcn_s_setprio(0);

#define BAR asm volatile("s_barrier" ::: "memory")

  f32x4 acc[8][4] = {};
  short8 af[8], bfv[8];
  const int NT = K >> 6;   // K-tiles of 64; even (16 or 64)

  // prologue: A(0), B(0), A(1) — 12 loads/thread
  STG_A4(0, 0);
  STG_B4(0, 0);
  STG_A4(1, 1);

  for (int j = 0; j < (NT >> 1); ++j) {
    const int T = 2 * j;
    const bool more  = (T + 2 < NT);
    const bool more3 = (T + 3 < NT);
    // ---- phA0: buf0, mh0 ----
    STG_B4(1, T + 1);
    asm volatile("s_waitcnt vmcnt(8)" ::: "memory");
    BAR;
    RD_AF(0, 0); RD_BF(0);
    MMAH(0);
    BAR;
    // ---- phB0: buf0, mh1 ----
    RD_AF(1, 0);
    if (more) STG_A4(0, T + 2);
    BAR;
    MMAH(1);
    BAR;
    // ---- phA1: buf1, mh0 ----
    if (more) {
      STG_B4(0, T + 2);
      asm volatile("s_waitcnt vmcnt(8)" ::: "memory");
    } else {
      asm volatile("s_waitcnt vmcnt(0)" ::: "memory");
    }
    BAR;
    RD_AF(0, 1); RD_BF(1);
    MMAH(0);
    BAR;
    // ---- phB1: buf1, mh1 ----
    RD_AF(1, 1);
    if (more3) STG_A4(1, T + 3);
    BAR;
    MMAH(1);
    BAR;
  }

  // ---- epilogue: direct stores ----
  const int row0 = bm * 256 + wm * 128 + fg * 4;
  const int col0 = bn * 256 + wn * 64 + fr;
  #pragma unroll
  for (int n = 0; n < 4; n++) {
    const int col = col0 + n * 16;
    const float bcol = bias[col];
    float lscale = 0.f;
    if (EPI == 2) lscale = lsg[col];
    #pragma unroll
    for (int m = 0; m < 8; m++) {
      #pragma unroll
      for (int r = 0; r < 4; r++) {
        const int row = row0 + m * 16 + r;
        float v = acc[m][n][r] + bcol;
        if (EPI == 0) {
          if (bn < 8) {
            ((unsigned short*)outp)[(size_t)row * 2048 + col] = f2bf(v);
          } else {
            const int d = col - 2048, hh = d >> 6, dd = d & 63;
            const int bb = row >> 10, nn = row & 1023;
            vtp[(((size_t)bb * 16 + hh) * 64 + dd) * 1024 + nn] = f2bf(v);
          }
        } else if (EPI == 1) {
          // gelu(v) ≈ v * sigmoid(2u), u = 0.79788456*(v + 0.044715 v^3)
          const float u = v * (0.7978845608f + 0.0356774081f * v * v);
          v = v * __builtin_amdgcn_rcpf(1.0f + __expf(-2.0f * u));
          ((unsigned short*)outp)[(size_t)row * N + col] = f2bf(v);
        } else {
          ((float*)outp)[(size_t)row * N + col] =
              resid[(size_t)row * N + col] + v * lscale;
        }
      }
    }
  }
#undef STG_A
#undef STG_B
#undef STG_A4
#undef STG_B4
#undef RD_AF
#undef RD_BF
#undef MMAH
#undef BAR
}

// ---------------- flash attention (no 1/sqrt(d) scale, faithful to ref) ----------------
// qk: [16384][2048] bf16 ; vT: [b][h][64 d][1024 n] bf16 ; out: [16384][1024] bf16
__global__ __launch_bounds__(512) void k_attn(const unsigned short* __restrict__ qk,
                                              const unsigned short* __restrict__ vT,
                                              unsigned short* __restrict__ out)
{
  const int qt = blockIdx.x;       // 0..3  (q tile of 256 rows)
  const int bh = blockIdx.y;       // 0..255
  const int b = bh >> 4, h = bh & 15;
  const int t = threadIdx.x, lane = t & 63, wid = t >> 6;
  const int fr = lane & 15, fg = lane >> 4;
  const int q0 = qt * 256 + wid * 32;

  __shared__ __align__(16) unsigned short Ksm[64 * 64];
  __shared__ __align__(16) unsigned short Vsm[64 * 64];
  __shared__ __align__(16) unsigned short plds[8][32][72];

  const size_t qbase = (size_t)b * 1024 * 2048 + (size_t)h * 64;
  const size_t kbase = qbase + 1024;
  const size_t vbase = (size_t)bh * 64 * 1024;

  short8 qf[2][2];
  #pragma unroll
  for (int m = 0; m < 2; m++)
    #pragma unroll
    for (int kh = 0; kh < 2; kh++)
      qf[m][kh] = *(const short8*)(qk + qbase + (size_t)(q0 + m*16 + fr) * 2048
                                   + kh*32 + fg*8);

  f32x4 oacc[2][4] = {};
  float mrow[2][4], lrow[2][4];
  #pragma unroll
  for (int m = 0; m < 2; m++)
    #pragma unroll
    for (int r = 0; r < 4; r++) { mrow[m][r] = -1e30f; lrow[m][r] = 0.f; }

  const int srow = t >> 3, sc = t & 7;
  const int scs = sc ^ (srow & 7);

  for (int kv0 = 0; kv0 < 1024; kv0 += 64) {
    __syncthreads();
    gload16(qk + kbase + (size_t)(kv0 + srow) * 2048 + scs*8, (char*)Ksm + t*16);
    gload16(vT + vbase + (size_t)srow * 1024 + kv0 + scs*8,   (char*)Vsm + t*16);
    __syncthreads();

    f32x4 sacc[2][4] = {};
    #pragma unroll
    for (int n = 0; n < 4; n++) {
      #pragma unroll
      for (int kh = 0; kh < 2; kh++) {
        const int krow = n*16 + fr;
        short8 kf = *(const short8*)&Ksm[krow*64 + (((kh*4 + fg) ^ (krow & 7)) * 8)];
        sacc[0][n] = MFMA16(qf[0][kh], kf, sacc[0][n]);
        sacc[1][n] = MFMA16(qf[1][kh], kf, sacc[1][n]);
      }
    }

    #pragma unroll
    for (int m = 0; m < 2; m++) {
      float pm[4];
      #pragma unroll
      for (int r = 0; r < 4; r++)
        pm[r] = fmaxf(fmaxf(sacc[m][0][r], sacc[m][1][r]),
                      fmaxf(sacc[m][2][r], sacc[m][3][r]));
      #pragma unroll
      for (int msk = 1; msk < 16; msk <<= 1)
        #pragma unroll
        for (int r = 0; r < 4; r++) pm[r] = fmaxf(pm[r], __shfl_xor(pm[r], msk));
      float corr[4];
      #pragma unroll
      for (int r = 0; r < 4; r++) {
        float mn = fmaxf(mrow[m][r], pm[r]);
        corr[r] = __expf(mrow[m][r] - mn);
        mrow[m][r] = mn;
      }
      float psum[4] = {0.f, 0.f, 0.f, 0.f};
      #pragma unroll
      for (int n = 0; n < 4; n++)
        #pragma unroll
        for (int r = 0; r < 4; r++) {
          float p = __expf(sacc[m][n][r] - mrow[m][r]);
          sacc[m][n][r] = p;
          psum[r] += p;
        }
      #pragma unroll
      for (int msk = 1; msk < 16; msk <<= 1)
        #pragma unroll
        for (int r = 0; r < 4; r++) psum[r] += __shfl_xor(psum[r], msk);
      #pragma unroll
      for (int r = 0; r < 4; r++) lrow[m][r] = lrow[m][r] * corr[r] + psum[r];
      #pragma unroll
      for (int d16 = 0; d16 < 4; d16++)
        #pragma unroll
        for (int r = 0; r < 4; r++) oacc[m][d16][r] *= corr[r];
      #pragma unroll
      for (int n = 0; n < 4; n++)
        #pragma unroll
        for (int r = 0; r < 4; r++)
          plds[wid][m*16 + fg*4 + r][n*16 + fr] = f2bf(sacc[m][n][r]);
    }

    short8 pf[2][2];
    #pragma unroll
    for (int m = 0; m < 2; m++)
      #pragma unroll
      for (int kh = 0; kh < 2; kh++)
        pf[m][kh] = *(const short8*)&plds[wid][m*16 + fr][kh*32 + fg*8];

    #pragma unroll
    for (int d16 = 0; d16 < 4; d16++) {
      #pragma unroll
      for (int kh = 0; kh < 2; kh++) {
        const int vrow = d16*16 + fr;
        short8 vf = *(const short8*)&Vsm[vrow*64 + (((kh*4 + fg) ^ (vrow & 7)) * 8)];
        oacc[0][d16] = MFMA16(pf[0][kh], vf, oacc[0][d16]);
        oacc[1][d16] = MFMA16(pf[1][kh], vf, oacc[1][d16]);
      }
    }
  }

  #pragma unroll
  for (int m = 0; m < 2; m++) {
    float inv[4];
    #pragma unroll
    for (int r = 0; r < 4; r++) inv[r] = 1.0f / lrow[m][r];
    #pragma unroll
    for (int d16 = 0; d16 < 4; d16++) {
      #pragma unroll
      for (int r = 0; r < 4; r++) {
        const int qrow = q0 + m*16 + fg*4 + r;
        const int col = h*64 + d16*16 + fr;
        out[(size_t)(b * 1024 + qrow) * 1024 + col] = f2bf(oacc[m][d16][r] * inv[r]);
      }
    }
  }
}

// ---------------- host launch ----------------
extern "C" void kernel_launch(void* const* d_in, const int* in_sizes, int n_in,
                              void* d_out, int out_size, void* d_ws, size_t ws_size,
                              hipStream_t stream) {
  const float* x      = (const float*)d_in[0];
  const float* ln1_g  = (const float*)d_in[1];
  const float* ln1_b  = (const float*)d_in[2];
  const float* qkv_w  = (const float*)d_in[3];
  const float* qkv_b  = (const float*)d_in[4];
  const float* proj_w = (const float*)d_in[5];
  const float* proj_b = (const float*)d_in[6];
  const float* ls1_g  = (const float*)d_in[7];
  const float* ln2_g  = (const float*)d_in[8];
  const float* ln2_b  = (const float*)d_in[9];
  const float* fc1_w  = (const float*)d_in[10];
  const float* fc1_b  = (const float*)d_in[11];
  const float* fc2_w  = (const float*)d_in[12];
  const float* fc2_b  = (const float*)d_in[13];
  const float* ls2_g  = (const float*)d_in[14];

  char* w = (char*)d_ws;
  unsigned short* wqkvT  = (unsigned short*)(w + 0);                    //  6,291,456
  unsigned short* wprojT = (unsigned short*)(w + 6291456);              //  2,097,152
  unsigned short* wfc1T  = (unsigned short*)(w + 8388608);              //  8,388,608
  unsigned short* wfc2T  = (unsigned short*)(w + 16777216);             //  8,388,608
  float*          x1     = (float*)(w + 25165824);                      // 67,108,864
  unsigned short* h1     = (unsigned short*)(w + 92274688);             // 33,554,432 (reused as h2)
  unsigned short* qkbuf  = (unsigned short*)(w + 125829120);            // 67,108,864 [16384][2048]
  unsigned short* vtbuf  = (unsigned short*)(w + 192937984);            // 33,554,432 [256][64][1024]
  unsigned short* attno  = (unsigned short*)(w + 226492416);            // 33,554,432
  unsigned short* h3     = (unsigned short*)(w + 125829120);            // 134,217,728 (overlays qk+vT)

  dim3 tb32(32, 8);
  k_transpose_cast<<<dim3(3072/32, 1024/32), tb32, 0, stream>>>(qkv_w,  wqkvT, 1024, 3072);
  k_transpose_cast<<<dim3(1024/32, 1024/32), tb32, 0, stream>>>(proj_w, wprojT, 1024, 1024);
  k_transpose_cast<<<dim3(4096/32, 1024/32), tb32, 0, stream>>>(fc1_w,  wfc1T, 1024, 4096);
  k_transpose_cast<<<dim3(1024/32, 4096/32), tb32, 0, stream>>>(fc2_w,  wfc2T, 4096, 1024);

  // LN1
  k_layernorm<<<16384, 256, 0, stream>>>(x, ln1_g, ln1_b, h1);
  // QKV = h1 @ qkv_w + qkv_b ; Q,K -> qkbuf, V -> vtbuf transposed
  k_gemm256<0><<<64*12, 512, 0, stream>>>(h1, wqkvT, qkv_b, nullptr, nullptr,
                                          qkbuf, vtbuf, 16384, 3072, 1024, 12);
  // attention
  k_attn<<<dim3(4, 256), 512, 0, stream>>>(qkbuf, vtbuf, attno);
  // x1 = x + (attn @ proj_w + proj_b) * ls1_g
  k_gemm256<2><<<64*4, 512, 0, stream>>>(attno, wprojT, proj_b, x, ls1_g,
                                         x1, nullptr, 16384, 1024, 1024, 4);
  // LN2
  k_layernorm<<<16384, 256, 0, stream>>>(x1, ln2_g, ln2_b, h1);
  // h3 = gelu(h2 @ fc1_w + fc1_b)
  k_gemm256<1><<<64*16, 512, 0, stream>>>(h1, wfc1T, fc1_b, nullptr, nullptr,
                                          h3, nullptr, 16384, 4096, 1024, 16);
  // out = x1 + (h3 @ fc2_w + fc2_b) * ls2_g
  k_gemm256<2><<<64*4, 512, 0, stream>>>(h3, wfc2T, fc2_b, x1, ls2_g,
                                         (float*)d_out, nullptr, 16384, 1024, 4096, 4);
}